// Round 1
// baseline (752.148 us; speedup 1.0000x reference)
//
#include <hip/hip_runtime.h>
#include <hip/hip_bf16.h>

#define B_ 4
#define N_ 65536
#define Q_ 400
#define C_ 20
#define M_ 64
#define QT 64
#define CHUNK 2048
#define NCHUNK (N_ / CHUNK)          // 32
#define NQT ((Q_ + QT - 1) / QT)     // 7
#define OFFSTRIDE (M_ + 2)           // 66

// fixed-point scales (int atomics are native; float atomics compile to CAS loops)
#define SX 8192.0f      // Xsum (raw logits) scale: 2^13
#define SS 32768.0f     // Ssum (sigmoid) scale: 2^15
#define SN 8192.0f      // negsum (softplus) scale: 2^13

// ---------------- Kernel A: per-(b,chunk) counting sort by instance id -------
// Produces perm[b][chunk][CHUNK] (u16 local row indices grouped by m) and
// binoff[b][chunk][65] (bin start offsets). Also folds in the old stats
// kernel: global per-(b,m) count + max(seg) (= class label).
__global__ __launch_bounds__(256) void sort_kernel(const int* __restrict__ inst,
                                                   const int* __restrict__ seg,
                                                   unsigned short* __restrict__ perm,
                                                   int* __restrict__ binoff,
                                                   int* __restrict__ cnt_g,
                                                   int* __restrict__ smax_g) {
    int b = blockIdx.x >> 5;        // NCHUNK = 32 chunks per batch
    int chunk = blockIdx.x & 31;
    __shared__ int hist[M_];
    __shared__ int smax[M_];
    __shared__ int cur[M_];
    __shared__ int off[M_ + 1];
    __shared__ unsigned short lperm[CHUNK];
    int tid = threadIdx.x;
    if (tid < M_) { hist[tid] = 0; smax[tid] = 0; }
    __syncthreads();

    int base = b * N_ + chunk * CHUNK;
    int mloc[CHUNK / 256];          // 8 elements per thread, static-indexed
#pragma unroll
    for (int i = 0; i < CHUNK / 256; ++i) {
        int idx = tid + i * 256;
        int m = inst[base + idx];
        int s = seg[base + idx];
        mloc[i] = m;
        atomicAdd(&hist[m], 1);
        atomicMax(&smax[m], s);
    }
    __syncthreads();

    if (tid == 0) {                  // serial 64-wide prefix: negligible
        int acc = 0;
        for (int m = 0; m < M_; ++m) { off[m] = acc; acc += hist[m]; }
        off[M_] = acc;
    }
    __syncthreads();
    if (tid < M_) cur[tid] = off[tid];
    __syncthreads();

#pragma unroll
    for (int i = 0; i < CHUNK / 256; ++i) {
        int idx = tid + i * 256;
        int pos = atomicAdd(&cur[mloc[i]], 1);   // intra-bin order irrelevant
        lperm[pos] = (unsigned short)idx;
    }
    __syncthreads();

    // coalesced write-out of the permutation (as u32 pairs)
    unsigned int* pg = (unsigned int*)(perm + ((size_t)b * NCHUNK + chunk) * CHUNK);
    const unsigned int* pl = (const unsigned int*)lperm;
    for (int i = tid; i < CHUNK / 2; i += 256) pg[i] = pl[i];

    int obase = (b * NCHUNK + chunk) * OFFSTRIDE;
    if (tid <= M_) binoff[obase + tid] = off[tid];
    if (tid < M_) {
        atomicAdd(&cnt_g[b * M_ + tid], hist[tid]);
        atomicMax(&smax_g[b * M_ + tid], smax[tid]);
    }
}

// ---------------- Kernel B: main pass over mask logits, sorted-bin walk ------
// 512 threads = 8 waves. Wave layout: lane = r*16 + c; c in [0,16) covers
// q0 = 4c..4c+3 (float4 load), r in [0,4) strides positions within a bin.
// Each wave owns bins m = wave + 8k. Bin id is implicit from the sort, so
// per-q sums of x and sigmoid(x) accumulate in f32 REGISTERS (no LDS atomics
// at all); one shfl-reduce + global atomic flush per (chunk, bin, q).
__global__ __launch_bounds__(512) void bin_kernel(const float* __restrict__ mask,
                                                  const unsigned short* __restrict__ perm,
                                                  const int* __restrict__ binoff,
                                                  int* __restrict__ xsum,
                                                  int* __restrict__ ssum,
                                                  int* __restrict__ negsum) {
    int chunk = blockIdx.x, qt = blockIdx.y, b = blockIdx.z;
    __shared__ unsigned short lperm[CHUNK];
    __shared__ int loff[M_ + 1];
    int tid = threadIdx.x;

    const unsigned int* pg = (const unsigned int*)(perm + ((size_t)b * NCHUNK + chunk) * CHUNK);
    unsigned int* pl = (unsigned int*)lperm;
    for (int i = tid; i < CHUNK / 2; i += 512) pl[i] = pg[i];
    if (tid <= M_) loff[tid] = binoff[(b * NCHUNK + chunk) * OFFSTRIDE + tid];
    __syncthreads();

    int lane = tid & 63, wave = tid >> 6;
    int r = lane >> 4, c = lane & 15;
    int q0 = qt * QT + 4 * c;
    bool qok = (q0 < Q_);
    const float* mbase = mask + ((size_t)b * N_ + (size_t)chunk * CHUNK) * Q_ + q0;
    float n0 = 0.f, n1 = 0.f, n2 = 0.f, n3 = 0.f;   // softplus accumulators

    if (qok) {
        for (int k = 0; k < M_ / 8; ++k) {
            int m = wave + 8 * k;
            int s = loff[m], e = loff[m + 1];
            float x0 = 0.f, x1 = 0.f, x2 = 0.f, x3 = 0.f;
            float g0 = 0.f, g1 = 0.f, g2 = 0.f, g3 = 0.f;
            int pos = s + r;
            // unroll-2: both perm reads + both row loads issued before math
            for (; pos + 4 < e; pos += 8) {
                int na = lperm[pos];
                int nb = lperm[pos + 4];
                float4 xa = *(const float4*)(mbase + (size_t)na * Q_);
                float4 xb = *(const float4*)(mbase + (size_t)nb * Q_);

                float ea0 = __expf(xa.x), ea1 = __expf(xa.y), ea2 = __expf(xa.z), ea3 = __expf(xa.w);
                float eb0 = __expf(xb.x), eb1 = __expf(xb.y), eb2 = __expf(xb.z), eb3 = __expf(xb.w);
                float ta0 = 1.f + ea0, ta1 = 1.f + ea1, ta2 = 1.f + ea2, ta3 = 1.f + ea3;
                float tb0 = 1.f + eb0, tb1 = 1.f + eb1, tb2 = 1.f + eb2, tb3 = 1.f + eb3;

                x0 += xa.x + xb.x; x1 += xa.y + xb.y;
                x2 += xa.z + xb.z; x3 += xa.w + xb.w;
                g0 += ea0 * __builtin_amdgcn_rcpf(ta0) + eb0 * __builtin_amdgcn_rcpf(tb0);
                g1 += ea1 * __builtin_amdgcn_rcpf(ta1) + eb1 * __builtin_amdgcn_rcpf(tb1);
                g2 += ea2 * __builtin_amdgcn_rcpf(ta2) + eb2 * __builtin_amdgcn_rcpf(tb2);
                g3 += ea3 * __builtin_amdgcn_rcpf(ta3) + eb3 * __builtin_amdgcn_rcpf(tb3);
                n0 += __logf(ta0) + __logf(tb0);
                n1 += __logf(ta1) + __logf(tb1);
                n2 += __logf(ta2) + __logf(tb2);
                n3 += __logf(ta3) + __logf(tb3);
            }
            if (pos < e) {
                int na = lperm[pos];
                float4 xa = *(const float4*)(mbase + (size_t)na * Q_);
                float ea0 = __expf(xa.x), ea1 = __expf(xa.y), ea2 = __expf(xa.z), ea3 = __expf(xa.w);
                float ta0 = 1.f + ea0, ta1 = 1.f + ea1, ta2 = 1.f + ea2, ta3 = 1.f + ea3;
                x0 += xa.x; x1 += xa.y; x2 += xa.z; x3 += xa.w;
                g0 += ea0 * __builtin_amdgcn_rcpf(ta0);
                g1 += ea1 * __builtin_amdgcn_rcpf(ta1);
                g2 += ea2 * __builtin_amdgcn_rcpf(ta2);
                g3 += ea3 * __builtin_amdgcn_rcpf(ta3);
                n0 += __logf(ta0); n1 += __logf(ta1);
                n2 += __logf(ta2); n3 += __logf(ta3);
            }
            // reduce partials across the 4 r-groups (lanes c, c+16, c+32, c+48)
            x0 += __shfl_xor(x0, 16); x0 += __shfl_xor(x0, 32);
            x1 += __shfl_xor(x1, 16); x1 += __shfl_xor(x1, 32);
            x2 += __shfl_xor(x2, 16); x2 += __shfl_xor(x2, 32);
            x3 += __shfl_xor(x3, 16); x3 += __shfl_xor(x3, 32);
            g0 += __shfl_xor(g0, 16); g0 += __shfl_xor(g0, 32);
            g1 += __shfl_xor(g1, 16); g1 += __shfl_xor(g1, 32);
            g2 += __shfl_xor(g2, 16); g2 += __shfl_xor(g2, 32);
            g3 += __shfl_xor(g3, 16); g3 += __shfl_xor(g3, 32);
            if (r == 0) {
                int bq = ((b * Q_ + q0) << 6) + m;
                atomicAdd(&xsum[bq + (0 << 6)], __float2int_rn(x0 * SX));
                atomicAdd(&xsum[bq + (1 << 6)], __float2int_rn(x1 * SX));
                atomicAdd(&xsum[bq + (2 << 6)], __float2int_rn(x2 * SX));
                atomicAdd(&xsum[bq + (3 << 6)], __float2int_rn(x3 * SX));
                atomicAdd(&ssum[bq + (0 << 6)], (int)__float2uint_rn(g0 * SS));
                atomicAdd(&ssum[bq + (1 << 6)], (int)__float2uint_rn(g1 * SS));
                atomicAdd(&ssum[bq + (2 << 6)], (int)__float2uint_rn(g2 * SS));
                atomicAdd(&ssum[bq + (3 << 6)], (int)__float2uint_rn(g3 * SS));
            }
        }
        // softplus row-sums (over all n of the chunk, all bins)
        n0 += __shfl_xor(n0, 16); n0 += __shfl_xor(n0, 32);
        n1 += __shfl_xor(n1, 16); n1 += __shfl_xor(n1, 32);
        n2 += __shfl_xor(n2, 16); n2 += __shfl_xor(n2, 32);
        n3 += __shfl_xor(n3, 16); n3 += __shfl_xor(n3, 32);
        if (r == 0) {
            atomicAdd(&negsum[b * Q_ + q0 + 0], __float2int_rn(n0 * SN));
            atomicAdd(&negsum[b * Q_ + q0 + 1], __float2int_rn(n1 * SN));
            atomicAdd(&negsum[b * Q_ + q0 + 2], __float2int_rn(n2 * SN));
            atomicAdd(&negsum[b * Q_ + q0 + 3], __float2int_rn(n3 * SN));
        }
    }
}

// ---------------- Kernel C: finalize cost[b][q][m] --------------------------
__global__ __launch_bounds__(64) void final_kernel(const float* __restrict__ cls_in,
                                                   const int* __restrict__ xsum,
                                                   const int* __restrict__ ssum,
                                                   const int* __restrict__ negsum,
                                                   const int* __restrict__ cnt_g,
                                                   const int* __restrict__ smax_g,
                                                   float* __restrict__ out) {
    int bq = blockIdx.x;
    int b = bq / Q_;
    int m = threadIdx.x;
    float Xs = (float)xsum[(bq << 6) + m] * (1.0f / SX);
    float Ss = (float)ssum[(bq << 6) + m] * (1.0f / SS);
    float sigsum = Ss;  // sum over m == sum over all n (every point has an instance)
    for (int off = 32; off; off >>= 1) sigsum += __shfl_xor(sigsum, off);

    __shared__ float cls[C_];
    if (m < C_) cls[m] = cls_in[bq * C_ + m];
    __syncthreads();
    float mx = cls[0];
    for (int i = 1; i < C_; ++i) mx = fmaxf(mx, cls[i]);
    float se = 0.f;
    for (int i = 0; i < C_; ++i) se += __expf(cls[i] - mx);
    int label = smax_g[b * M_ + m];
    float p = __expf(cls[label] - mx) / se;

    float negf = (float)negsum[bq] * (1.0f / SN);
    float cm = (negf - Xs) * (1.f / (float)N_);
    float cd = 1.f - (2.f * Ss + 1.f) / (sigsum + (float)cnt_g[b * M_ + m] + 1.f);
    out[(bq << 6) + m] = cm + (1.f - p) + cd;
}

extern "C" void kernel_launch(void* const* d_in, const int* in_sizes, int n_in,
                              void* d_out, int out_size, void* d_ws, size_t ws_size,
                              hipStream_t stream) {
    const float* mask = (const float*)d_in[0];   // [B, N, Q] f32
    const float* cls  = (const float*)d_in[1];   // [B, Q, C] f32
    const int*   inst = (const int*)d_in[2];     // [B, N] i32
    const int*   seg  = (const int*)d_in[3];     // [B, N] i32
    float* out = (float*)d_out;                  // [B, Q, M] f32

    int* xsum   = (int*)d_ws;                    // B*Q*M
    int* ssum   = xsum + B_ * Q_ * M_;           // B*Q*M
    int* negsum = ssum + B_ * Q_ * M_;           // B*Q
    int* cnt_g  = negsum + B_ * Q_;              // B*M
    int* smax_g = cnt_g + B_ * M_;               // B*M
    int* binoff = smax_g + B_ * M_;              // B*NCHUNK*OFFSTRIDE
    unsigned short* perm = (unsigned short*)(binoff + B_ * NCHUNK * OFFSTRIDE);  // B*N u16

    // zero only the accumulators (binoff/perm are fully overwritten)
    size_t zbytes = (size_t)(2 * B_ * Q_ * M_ + B_ * Q_ + 2 * B_ * M_) * 4;
    hipMemsetAsync(d_ws, 0, zbytes, stream);

    sort_kernel<<<B_ * NCHUNK, 256, 0, stream>>>(inst, seg, perm, binoff, cnt_g, smax_g);
    bin_kernel<<<dim3(NCHUNK, NQT, B_), 512, 0, stream>>>(mask, perm, binoff, xsum, ssum, negsum);
    final_kernel<<<B_ * Q_, 64, 0, stream>>>(cls, xsum, ssum, negsum, cnt_g, smax_g, out);
}

// Round 2
// 615.677 us; speedup vs baseline: 1.2217x; 1.2217x over previous
//
#include <hip/hip_runtime.h>
#include <hip/hip_bf16.h>

#define B_ 4
#define N_ 65536
#define Q_ 400
#define C_ 20
#define M_ 64
#define QT 64
#define CHUNK 2048
#define NCHUNK (N_ / CHUNK)          // 32
#define NQT ((Q_ + QT - 1) / QT)     // 7
#define OFFSTRIDE (M_ + 2)           // 66

// fixed-point scales (int atomics are native; float atomics compile to CAS loops)
#define SX 8192.0f      // x (raw logits) scale: 2^13 (hi word of packed u64, signed)
#define SS 32768.0f     // sigmoid scale: 2^15 (lo word of packed u64, unsigned)
#define SN 8192.0f      // negsum (softplus) scale: 2^13

// pack per-flush (x, sig) sums into one u64: hi = s32 x*SX, lo = u32 sig*SS.
// lo-word totals stay < 2^26 (max ~1200 rows x 32768) so no carry into hi;
// negative hi contributions wrap correctly in two's complement.
#define PACK(x, g) ((((unsigned long long)(unsigned int)__float2int_rn((x) * SX)) << 32) \
                    | (unsigned long long)(unsigned int)__float2uint_rn((g) * SS))

// ---------------- Kernel A: per-(b,chunk) counting sort by instance id -------
__global__ __launch_bounds__(256) void sort_kernel(const int* __restrict__ inst,
                                                   const int* __restrict__ seg,
                                                   unsigned short* __restrict__ perm,
                                                   int* __restrict__ binoff,
                                                   int* __restrict__ cnt_g,
                                                   int* __restrict__ smax_g) {
    int b = blockIdx.x >> 5;        // NCHUNK = 32 chunks per batch
    int chunk = blockIdx.x & 31;
    __shared__ int hist[M_];
    __shared__ int smax[M_];
    __shared__ int cur[M_];
    __shared__ int off[M_ + 1];
    __shared__ unsigned short lperm[CHUNK];
    int tid = threadIdx.x;
    if (tid < M_) { hist[tid] = 0; smax[tid] = 0; }
    __syncthreads();

    int base = b * N_ + chunk * CHUNK;
    int mloc[CHUNK / 256];          // 8 elements per thread, static-indexed
#pragma unroll
    for (int i = 0; i < CHUNK / 256; ++i) {
        int idx = tid + i * 256;
        int m = inst[base + idx];
        int s = seg[base + idx];
        mloc[i] = m;
        atomicAdd(&hist[m], 1);
        atomicMax(&smax[m], s);
    }
    __syncthreads();

    if (tid == 0) {                  // serial 64-wide prefix: negligible
        int acc = 0;
        for (int m = 0; m < M_; ++m) { off[m] = acc; acc += hist[m]; }
        off[M_] = acc;
    }
    __syncthreads();
    if (tid < M_) cur[tid] = off[tid];
    __syncthreads();

#pragma unroll
    for (int i = 0; i < CHUNK / 256; ++i) {
        int idx = tid + i * 256;
        int pos = atomicAdd(&cur[mloc[i]], 1);   // intra-bin order irrelevant
        lperm[pos] = (unsigned short)idx;
    }
    __syncthreads();

    unsigned int* pg = (unsigned int*)(perm + ((size_t)b * NCHUNK + chunk) * CHUNK);
    const unsigned int* pl = (const unsigned int*)lperm;
    for (int i = tid; i < CHUNK / 2; i += 256) pg[i] = pl[i];

    int obase = (b * NCHUNK + chunk) * OFFSTRIDE;
    if (tid <= M_) binoff[obase + tid] = off[tid];
    if (tid < M_) {
        atomicAdd(&cnt_g[b * M_ + tid], hist[tid]);
        atomicMax(&smax_g[b * M_ + tid], smax[tid]);
    }
}

// ---------------- Kernel B: main pass over mask logits, walker-per-bin -------
// 512 threads = 8 waves x 4 r-groups = 32 walkers. Walker w handles bin
// m = mhalf*32 + w alone: its 16 lanes (c) share each row (broadcast lperm
// read), cover q0=qt*64+4c..+3 via float4. Unroll-4 keeps 16 independent
// 256B loads in flight per wave. x/sig accumulate in registers per lane (q
// is final -> no shuffles); flush = 4 packed-u64 global atomics per lane.
__global__ __launch_bounds__(512) void bin_kernel(const float* __restrict__ mask,
                                                  const unsigned short* __restrict__ perm,
                                                  const int* __restrict__ binoff,
                                                  unsigned long long* __restrict__ xs_packed,
                                                  int* __restrict__ negsum) {
    int chunk = blockIdx.x, qt = blockIdx.y;
    int b = blockIdx.z >> 1, mhalf = blockIdx.z & 1;
    __shared__ unsigned short lperm[CHUNK];
    __shared__ int loff[M_ + 1];
    int tid = threadIdx.x;

    const unsigned int* pg = (const unsigned int*)(perm + ((size_t)b * NCHUNK + chunk) * CHUNK);
    unsigned int* pl = (unsigned int*)lperm;
    for (int i = tid; i < CHUNK / 2; i += 512) pl[i] = pg[i];
    if (tid <= M_) loff[tid] = binoff[(b * NCHUNK + chunk) * OFFSTRIDE + tid];
    __syncthreads();

    int lane = tid & 63, wave = tid >> 6;
    int r = lane >> 4, c = lane & 15;
    int m = mhalf * 32 + wave * 4 + r;     // this walker's bin
    int q0 = qt * QT + 4 * c;
    bool qok = (q0 < Q_);
    const float* mbase = mask + ((size_t)b * N_ + (size_t)chunk * CHUNK) * Q_ + q0;

    float x0 = 0.f, x1 = 0.f, x2 = 0.f, x3 = 0.f;
    float g0 = 0.f, g1 = 0.f, g2 = 0.f, g3 = 0.f;
    float n0 = 0.f, n1 = 0.f, n2 = 0.f, n3 = 0.f;

#define ACC4(v) { \
    float e0 = __expf(v.x), e1 = __expf(v.y), e2 = __expf(v.z), e3 = __expf(v.w); \
    float t0 = 1.f + e0, t1 = 1.f + e1, t2 = 1.f + e2, t3 = 1.f + e3; \
    x0 += v.x; x1 += v.y; x2 += v.z; x3 += v.w; \
    g0 += e0 * __builtin_amdgcn_rcpf(t0); g1 += e1 * __builtin_amdgcn_rcpf(t1); \
    g2 += e2 * __builtin_amdgcn_rcpf(t2); g3 += e3 * __builtin_amdgcn_rcpf(t3); \
    n0 += __logf(t0); n1 += __logf(t1); n2 += __logf(t2); n3 += __logf(t3); }

    if (qok) {
        int s = loff[m], e = loff[m + 1];
        int pos = s;
        for (; pos + 3 < e; pos += 4) {
            int ia = lperm[pos], ib = lperm[pos + 1];
            int ic = lperm[pos + 2], id = lperm[pos + 3];
            float4 va = *(const float4*)(mbase + (size_t)ia * Q_);
            float4 vb = *(const float4*)(mbase + (size_t)ib * Q_);
            float4 vc = *(const float4*)(mbase + (size_t)ic * Q_);
            float4 vd = *(const float4*)(mbase + (size_t)id * Q_);
            ACC4(va) ACC4(vb) ACC4(vc) ACC4(vd)
        }
        for (; pos < e; ++pos) {
            int ia = lperm[pos];
            float4 va = *(const float4*)(mbase + (size_t)ia * Q_);
            ACC4(va)
        }

        // flush x/sig: lane's q is final, bin m is this walker's -> direct atomics
        unsigned long long* dst = xs_packed + (size_t)(((b * Q_ + q0) << 6) + m);
        atomicAdd(dst + (0 << 6), PACK(x0, g0));
        atomicAdd(dst + (1 << 6), PACK(x1, g1));
        atomicAdd(dst + (2 << 6), PACK(x2, g2));
        atomicAdd(dst + (3 << 6), PACK(x3, g3));

        // softplus row-sums: reduce the 4 walkers (r-groups) of this wave,
        // which share the same q range but own different bins
        n0 += __shfl_xor(n0, 16); n0 += __shfl_xor(n0, 32);
        n1 += __shfl_xor(n1, 16); n1 += __shfl_xor(n1, 32);
        n2 += __shfl_xor(n2, 16); n2 += __shfl_xor(n2, 32);
        n3 += __shfl_xor(n3, 16); n3 += __shfl_xor(n3, 32);
        if (r == 0) {
            atomicAdd(&negsum[b * Q_ + q0 + 0], __float2int_rn(n0 * SN));
            atomicAdd(&negsum[b * Q_ + q0 + 1], __float2int_rn(n1 * SN));
            atomicAdd(&negsum[b * Q_ + q0 + 2], __float2int_rn(n2 * SN));
            atomicAdd(&negsum[b * Q_ + q0 + 3], __float2int_rn(n3 * SN));
        }
    }
#undef ACC4
}

// ---------------- Kernel C: finalize cost[b][q][m] --------------------------
__global__ __launch_bounds__(64) void final_kernel(const float* __restrict__ cls_in,
                                                   const unsigned long long* __restrict__ xs_packed,
                                                   const int* __restrict__ negsum,
                                                   const int* __restrict__ cnt_g,
                                                   const int* __restrict__ smax_g,
                                                   float* __restrict__ out) {
    int bq = blockIdx.x;
    int b = bq / Q_;
    int m = threadIdx.x;
    unsigned long long v = xs_packed[(bq << 6) + m];
    float Xs = (float)(int)(v >> 32) * (1.0f / SX);
    float Ss = (float)(unsigned int)(v & 0xffffffffull) * (1.0f / SS);
    float sigsum = Ss;  // sum over m == sum over all n (every point has an instance)
    for (int off = 32; off; off >>= 1) sigsum += __shfl_xor(sigsum, off);

    __shared__ float cls[C_];
    if (m < C_) cls[m] = cls_in[bq * C_ + m];
    __syncthreads();
    float mx = cls[0];
    for (int i = 1; i < C_; ++i) mx = fmaxf(mx, cls[i]);
    float se = 0.f;
    for (int i = 0; i < C_; ++i) se += __expf(cls[i] - mx);
    int label = smax_g[b * M_ + m];
    float p = __expf(cls[label] - mx) / se;

    float negf = (float)negsum[bq] * (1.0f / SN);
    float cm = (negf - Xs) * (1.f / (float)N_);
    float cd = 1.f - (2.f * Ss + 1.f) / (sigsum + (float)cnt_g[b * M_ + m] + 1.f);
    out[(bq << 6) + m] = cm + (1.f - p) + cd;
}

extern "C" void kernel_launch(void* const* d_in, const int* in_sizes, int n_in,
                              void* d_out, int out_size, void* d_ws, size_t ws_size,
                              hipStream_t stream) {
    const float* mask = (const float*)d_in[0];   // [B, N, Q] f32
    const float* cls  = (const float*)d_in[1];   // [B, Q, C] f32
    const int*   inst = (const int*)d_in[2];     // [B, N] i32
    const int*   seg  = (const int*)d_in[3];     // [B, N] i32
    float* out = (float*)d_out;                  // [B, Q, M] f32

    unsigned long long* xs_packed = (unsigned long long*)d_ws;       // B*Q*M u64
    int* negsum = (int*)(xs_packed + B_ * Q_ * M_);                  // B*Q
    int* cnt_g  = negsum + B_ * Q_;                                  // B*M
    int* smax_g = cnt_g + B_ * M_;                                   // B*M
    int* binoff = smax_g + B_ * M_;                                  // B*NCHUNK*OFFSTRIDE
    unsigned short* perm = (unsigned short*)(binoff + B_ * NCHUNK * OFFSTRIDE);  // B*N u16

    // zero only the accumulators (binoff/perm are fully overwritten)
    size_t zbytes = (size_t)B_ * Q_ * M_ * 8 + (size_t)(B_ * Q_ + 2 * B_ * M_) * 4;
    hipMemsetAsync(d_ws, 0, zbytes, stream);

    sort_kernel<<<B_ * NCHUNK, 256, 0, stream>>>(inst, seg, perm, binoff, cnt_g, smax_g);
    bin_kernel<<<dim3(NCHUNK, NQT, B_ * 2), 512, 0, stream>>>(mask, perm, binoff, xs_packed, negsum);
    final_kernel<<<B_ * Q_, 64, 0, stream>>>(cls, xs_packed, negsum, cnt_g, smax_g, out);
}